// Round 10
// baseline (1514.781 us; speedup 1.0000x reference)
//
#include <hip/hip_runtime.h>

#define T_SEQ 512
#define B_BAT 256
#define ED_ 100
#define NVOC 32000
#define DT_C 1e-3f
#define SC_C 0.2f
#define MU_C 1.0f
#define NSTEP 20
#define CCH 8                 // tokens per pipeline chunk
#define NCH (T_SEQ / CCH)     // 64 chunks

typedef float v2f __attribute__((ext_vector_type(2)));
typedef float v4f __attribute__((ext_vector_type(4)));

// packed FMA, scalar splat from LO half of pair sv:  acc.{x,y} += sv.x * w.{x,y}
#define PK_FMA_LO(acc, sv, w)                                                  \
    asm("v_pk_fma_f32 %0, %1, %2, %0 op_sel:[0,0,0] op_sel_hi:[0,1,1]"         \
        : "+v"(acc) : "v"(sv), "v"(w))
// packed FMA, scalar splat from HI half of pair sv:  acc.{x,y} += sv.y * w.{x,y}
#define PK_FMA_HI(acc, sv, w)                                                  \
    asm("v_pk_fma_f32 %0, %1, %2, %0 op_sel:[1,0,0] op_sel_hi:[1,1,1]"         \
        : "+v"(acc) : "v"(sv), "v"(w))

__device__ __forceinline__ float fast_tanh(float x) {
    float e = __expf(2.f * x);
    return 1.f - 2.f * __builtin_amdgcn_rcpf(e + 1.f);
}

// ---------------------------------------------------------------------------
// K0: tab[v][c] = relu(E[v] @ W1cat + b1cat), c interleaved (2u+p). 250 blocks.
// ---------------------------------------------------------------------------
__global__ __launch_bounds__(256) void k0_table(
    const float* __restrict__ E,
    const float* __restrict__ W1r, const float* __restrict__ b1r,
    const float* __restrict__ W1i, const float* __restrict__ b1i,
    float* __restrict__ tab)
{
    __shared__ float embT[128 * 104];
    __shared__ float Wc[100 * 128];
    __shared__ float bias[128];
    const int tid = threadIdx.x;
    const int row0g = blockIdx.x * 128;

    for (int idx = tid; idx < 100 * 128; idx += 256) {
        int k = idx >> 7, c = idx & 127;
        Wc[idx] = (c & 1) ? W1i[k * 64 + (c >> 1)] : W1r[k * 64 + (c >> 1)];
    }
    if (tid < 128) bias[tid] = (tid & 1) ? b1i[tid >> 1] : b1r[tid >> 1];
    {
        int r = tid >> 1, half = tid & 1;
        const float4* src = (const float4*)(E + (size_t)(row0g + r) * ED_);
        float4* dst = (float4*)&embT[r * 104];
        for (int j = half; j < 25; j += 2) dst[j] = src[j];
    }
    __syncthreads();

    const int col0 = (tid & 15) * 8;
    const int row0 = (tid >> 4) * 8;
    float acc[8][8];
#pragma unroll
    for (int i = 0; i < 8; ++i)
#pragma unroll
        for (int j = 0; j < 8; ++j) acc[i][j] = 0.f;

    for (int k0 = 0; k0 < 100; k0 += 4) {
        float ev[8][4];
#pragma unroll
        for (int i = 0; i < 8; ++i)
            *(float4*)ev[i] = *(const float4*)&embT[(row0 + i) * 104 + k0];
#pragma unroll
        for (int kk = 0; kk < 4; ++kk) {
            float4 wA = *(const float4*)&Wc[(k0 + kk) * 128 + col0];
            float4 wB = *(const float4*)&Wc[(k0 + kk) * 128 + col0 + 4];
#pragma unroll
            for (int i = 0; i < 8; ++i) {
                float e = ev[i][kk];
                acc[i][0] = fmaf(e, wA.x, acc[i][0]);
                acc[i][1] = fmaf(e, wA.y, acc[i][1]);
                acc[i][2] = fmaf(e, wA.z, acc[i][2]);
                acc[i][3] = fmaf(e, wA.w, acc[i][3]);
                acc[i][4] = fmaf(e, wB.x, acc[i][4]);
                acc[i][5] = fmaf(e, wB.y, acc[i][5]);
                acc[i][6] = fmaf(e, wB.z, acc[i][6]);
                acc[i][7] = fmaf(e, wB.w, acc[i][7]);
            }
        }
    }
#pragma unroll
    for (int i = 0; i < 8; ++i) {
        float4 o0, o1;
        o0.x = fmaxf(acc[i][0] + bias[col0 + 0], 0.f);
        o0.y = fmaxf(acc[i][1] + bias[col0 + 1], 0.f);
        o0.z = fmaxf(acc[i][2] + bias[col0 + 2], 0.f);
        o0.w = fmaxf(acc[i][3] + bias[col0 + 3], 0.f);
        o1.x = fmaxf(acc[i][4] + bias[col0 + 4], 0.f);
        o1.y = fmaxf(acc[i][5] + bias[col0 + 5], 0.f);
        o1.z = fmaxf(acc[i][6] + bias[col0 + 6], 0.f);
        o1.w = fmaxf(acc[i][7] + bias[col0 + 7], 0.f);
        size_t base = (size_t)(row0g + row0 + i) * 128 + col0;
        *(float4*)&tab[base] = o0;
        *(float4*)&tab[base + 4] = o1;
    }
}

// ---------------------------------------------------------------------------
// Split pipeline: 512 blocks x 256 threads (4 waves). Blocks 0..255 = family1
// (hopf1, h1-GEMM, x2-GEMM x2) for batch b = blockIdx; blocks 256..511 =
// family2 (hopf2, h2-GEMM, h3/out x2) for b = blockIdx-256. x2 handoff via
// global x2g + per-batch release/acquire flags (producer never blocks).
// Weights register-resident in a role-shared wsh[64] (full-unrolled indexing).
// ---------------------------------------------------------------------------
__global__ __launch_bounds__(256, 2) void donn_split(
    const float* __restrict__ tab, const int* __restrict__ xin,
    const float* __restrict__ om1, const float* __restrict__ om2,
    const float* __restrict__ Wp1, const float* __restrict__ bp1,
    const float* __restrict__ W2r, const float* __restrict__ b2r,
    const float* __restrict__ W2i, const float* __restrict__ b2i,
    const float* __restrict__ Wp2, const float* __restrict__ bp2,
    const float* __restrict__ Wpr, const float* __restrict__ bpr,
    const float* __restrict__ Wh,  const float* __restrict__ bh,
    float* __restrict__ x2g, int* flags, float* __restrict__ out)
{
    // shared by both families (a block is only ever one family)
    __shared__ __align__(16) v2f   WpL[64 * 32];        // k 64..127 (permuted)
    __shared__ __align__(16) float fbuf[2][CCH][128];   // forcing ring
    __shared__ __align__(16) float zring[2][CCH][128];  // z1 / z2 ring
    __shared__ __align__(16) float hbuf[2][CCH][64];    // h1 / h2 ring
    __shared__ float h3b[2][CCH][20];
    __shared__ float Whs[40], bhs[2];

    const int fam = blockIdx.x >> 8;         // 0 = layer1, 1 = layer2
    const int b   = blockIdx.x & 255;
    const int tid = threadIdx.x, wid = tid >> 6, lane = tid & 63;
    const int* xb = xin + b * T_SEQ;
    const int cp = lane & 31, u = lane, jj = lane % 20;

    const float* Wp = fam ? Wp2 : Wp1;
    for (int idx = tid; idx < 64 * 32; idx += 256) {
        int kI = (idx >> 5) + 64, cp2 = idx & 31;
        int kR = (kI & 1) * 64 + (kI >> 1);
        WpL[idx] = (v2f){ Wp[kR * 64 + 2 * cp2], Wp[kR * 64 + 2 * cp2 + 1] };
    }
    if (fam) { if (tid < 40) Whs[tid] = Wh[tid]; if (tid < 2) bhs[tid] = bh[tid]; }

    // role-shared register weight array (all indexing full-unrolled/static)
    v2f wsh[64];
    v2f breg = {0.f, 0.f};
    float bscal = 0.f;
    if (wid == 1) {
#pragma unroll
        for (int kI = 0; kI < 64; ++kI) {
            int kR = (kI & 1) * 64 + (kI >> 1);
            wsh[kI] = *(const v2f*)&Wp[kR * 64 + 2 * cp];
        }
        breg = fam ? (v2f){ bp2[2*cp], bp2[2*cp+1] }
                   : (v2f){ bp1[2*cp], bp1[2*cp+1] };
    } else if (wid >= 2) {
        if (!fam) {
#pragma unroll
            for (int k = 0; k < 64; ++k)
                wsh[k] = (v2f){ W2r[k * 64 + u], W2i[k * 64 + u] };
            breg = (v2f){ b2r[u], b2i[u] };
        } else {
#pragma unroll
            for (int kq = 0; kq < 16; ++kq) {
                wsh[2*kq]   = (v2f){ Wpr[(4*kq+0)*20 + jj], Wpr[(4*kq+1)*20 + jj] };
                wsh[2*kq+1] = (v2f){ Wpr[(4*kq+2)*20 + jj], Wpr[(4*kq+3)*20 + jj] };
            }
            bscal = bpr[jj];
        }
    }

    const float C1 = 1.0f + DT_C * MU_C;
    const float SD = DT_C * SC_C;
    v2f zH = { 0.1f, 0.0f };
    float domH = 0.f;
    if (wid == 0) domH = DT_C * (fam ? om2[lane] : om1[lane]);

    if (!fam && wid == 0) {    // prologue: stage chunk-0 forcing from tab
        const float* tl = tab + 2 * lane;
        v2f g0 = *(const v2f*)(tl + (size_t)xb[0] * 128);
        v2f g1 = *(const v2f*)(tl + (size_t)xb[1] * 128);
        v2f g2 = *(const v2f*)(tl + (size_t)xb[2] * 128);
        v2f g3 = *(const v2f*)(tl + (size_t)xb[3] * 128);
        v2f g4 = *(const v2f*)(tl + (size_t)xb[4] * 128);
        v2f g5 = *(const v2f*)(tl + (size_t)xb[5] * 128);
        v2f g6 = *(const v2f*)(tl + (size_t)xb[6] * 128);
        v2f g7 = *(const v2f*)(tl + (size_t)xb[7] * 128);
        *(v2f*)&fbuf[0][0][2*lane] = g0; *(v2f*)&fbuf[0][1][2*lane] = g1;
        *(v2f*)&fbuf[0][2][2*lane] = g2; *(v2f*)&fbuf[0][3][2*lane] = g3;
        *(v2f*)&fbuf[0][4][2*lane] = g4; *(v2f*)&fbuf[0][5][2*lane] = g5;
        *(v2f*)&fbuf[0][6][2*lane] = g6; *(v2f*)&fbuf[0][7][2*lane] = g7;
    }
    __syncthreads();

    if (!fam) {
        // ================== family 1: hopf1 -> h1 -> x2 ==================
        int* myflag = flags + ((wid == 2) ? b : 256 + b);
        for (int it = 0; it < NCH + 2; ++it) {
            if (wid == 0) {                  // hopf1, chunk it
                const int c = it;
                if (c < NCH) {
                    const int s = c & 1;
                    const int cn = (c + 1 < NCH) ? (c + 1) : (NCH - 1);
                    const int sn = cn & 1;
                    const float* tl = tab + 2 * lane;
                    const int* xc = xb + cn * 8;
                    v2f g0 = *(const v2f*)(tl + (size_t)xc[0] * 128);
                    v2f g1 = *(const v2f*)(tl + (size_t)xc[1] * 128);
                    v2f g2 = *(const v2f*)(tl + (size_t)xc[2] * 128);
                    v2f g3 = *(const v2f*)(tl + (size_t)xc[3] * 128);
                    v2f g4 = *(const v2f*)(tl + (size_t)xc[4] * 128);
                    v2f g5 = *(const v2f*)(tl + (size_t)xc[5] * 128);
                    v2f g6 = *(const v2f*)(tl + (size_t)xc[6] * 128);
                    v2f g7 = *(const v2f*)(tl + (size_t)xc[7] * 128);
                    for (int j = 0; j < CCH; ++j) {
                        v2f f = *(const v2f*)&fbuf[s][j][2*lane];
                        const float dcr = SD * f.x, dci = SD * f.y;
                        float zr = zH.x, zi = zH.y;
#pragma unroll 2
                        for (int st = 0; st < NSTEP; ++st) {
                            float wr = fmaf(-domH, zi, dcr);
                            float wi = fmaf( domH, zr, dci);
                            float r2 = fmaf(zr, zr, zi * zi);
                            float g  = fmaf(-DT_C, r2, C1);
                            zr = fmaf(g, zr, wr);
                            zi = fmaf(g, zi, wi);
                        }
                        zH.x = zr; zH.y = zi;
                        *(v2f*)&zring[s][j][2*lane] = zH;
                    }
                    *(v2f*)&fbuf[sn][0][2*lane] = g0;
                    *(v2f*)&fbuf[sn][1][2*lane] = g1;
                    *(v2f*)&fbuf[sn][2][2*lane] = g2;
                    *(v2f*)&fbuf[sn][3][2*lane] = g3;
                    *(v2f*)&fbuf[sn][4][2*lane] = g4;
                    *(v2f*)&fbuf[sn][5][2*lane] = g5;
                    *(v2f*)&fbuf[sn][6][2*lane] = g6;
                    *(v2f*)&fbuf[sn][7][2*lane] = g7;
                }
            } else if (wid == 1) {           // h1 GEMM, chunk it-1
                const int c = it - 1;
                if (0 <= c && c < NCH) {
                    const int s = c & 1;
                    const int rg = lane >> 5, r0 = rg * 4;
                    v2f a0 = {0,0}, a1 = {0,0}, a2 = {0,0}, a3 = {0,0};
#pragma unroll
                    for (int kq = 0; kq < 16; ++kq) {   // reg-weight half
                        v4f zv0 = *(const v4f*)&zring[s][r0+0][4*kq];
                        v4f zv1 = *(const v4f*)&zring[s][r0+1][4*kq];
                        v4f zv2 = *(const v4f*)&zring[s][r0+2][4*kq];
                        v4f zv3 = *(const v4f*)&zring[s][r0+3][4*kq];
                        PK_FMA_LO(a0, zv0.xy, wsh[4*kq+0]); PK_FMA_HI(a0, zv0.xy, wsh[4*kq+1]);
                        PK_FMA_LO(a0, zv0.zw, wsh[4*kq+2]); PK_FMA_HI(a0, zv0.zw, wsh[4*kq+3]);
                        PK_FMA_LO(a1, zv1.xy, wsh[4*kq+0]); PK_FMA_HI(a1, zv1.xy, wsh[4*kq+1]);
                        PK_FMA_LO(a1, zv1.zw, wsh[4*kq+2]); PK_FMA_HI(a1, zv1.zw, wsh[4*kq+3]);
                        PK_FMA_LO(a2, zv2.xy, wsh[4*kq+0]); PK_FMA_HI(a2, zv2.xy, wsh[4*kq+1]);
                        PK_FMA_LO(a2, zv2.zw, wsh[4*kq+2]); PK_FMA_HI(a2, zv2.zw, wsh[4*kq+3]);
                        PK_FMA_LO(a3, zv3.xy, wsh[4*kq+0]); PK_FMA_HI(a3, zv3.xy, wsh[4*kq+1]);
                        PK_FMA_LO(a3, zv3.zw, wsh[4*kq+2]); PK_FMA_HI(a3, zv3.zw, wsh[4*kq+3]);
                    }
#pragma unroll 4
                    for (int kq = 16; kq < 32; ++kq) {  // LDS-weight half
                        v4f zv0 = *(const v4f*)&zring[s][r0+0][4*kq];
                        v4f zv1 = *(const v4f*)&zring[s][r0+1][4*kq];
                        v4f zv2 = *(const v4f*)&zring[s][r0+2][4*kq];
                        v4f zv3 = *(const v4f*)&zring[s][r0+3][4*kq];
                        v2f w0 = WpL[(4*kq-64)*32 + cp];
                        v2f w1 = WpL[(4*kq-63)*32 + cp];
                        v2f w2 = WpL[(4*kq-62)*32 + cp];
                        v2f w3 = WpL[(4*kq-61)*32 + cp];
                        PK_FMA_LO(a0, zv0.xy, w0); PK_FMA_HI(a0, zv0.xy, w1);
                        PK_FMA_LO(a0, zv0.zw, w2); PK_FMA_HI(a0, zv0.zw, w3);
                        PK_FMA_LO(a1, zv1.xy, w0); PK_FMA_HI(a1, zv1.xy, w1);
                        PK_FMA_LO(a1, zv1.zw, w2); PK_FMA_HI(a1, zv1.zw, w3);
                        PK_FMA_LO(a2, zv2.xy, w0); PK_FMA_HI(a2, zv2.xy, w1);
                        PK_FMA_LO(a2, zv2.zw, w2); PK_FMA_HI(a2, zv2.zw, w3);
                        PK_FMA_LO(a3, zv3.xy, w0); PK_FMA_HI(a3, zv3.xy, w1);
                        PK_FMA_LO(a3, zv3.zw, w2); PK_FMA_HI(a3, zv3.zw, w3);
                    }
                    v2f o0 = { fmaxf(a0.x + breg.x, 0.f), fmaxf(a0.y + breg.y, 0.f) };
                    v2f o1 = { fmaxf(a1.x + breg.x, 0.f), fmaxf(a1.y + breg.y, 0.f) };
                    v2f o2 = { fmaxf(a2.x + breg.x, 0.f), fmaxf(a2.y + breg.y, 0.f) };
                    v2f o3 = { fmaxf(a3.x + breg.x, 0.f), fmaxf(a3.y + breg.y, 0.f) };
                    *(v2f*)&hbuf[s][r0+0][2*cp] = o0;
                    *(v2f*)&hbuf[s][r0+1][2*cp] = o1;
                    *(v2f*)&hbuf[s][r0+2][2*cp] = o2;
                    *(v2f*)&hbuf[s][r0+3][2*cp] = o3;
                }
            } else {                         // x2 GEMM, chunk it-2 -> global
                const int c = it - 2;
                if (0 <= c && c < NCH) {
                    const int s = c & 1, rb = (wid - 2) * 4;
                    v2f a0 = {0,0}, a1 = {0,0}, a2 = {0,0}, a3 = {0,0};
#pragma unroll
                    for (int kq = 0; kq < 16; ++kq) {
                        v4f h0  = *(const v4f*)&hbuf[s][rb+0][4*kq];
                        v4f h1v = *(const v4f*)&hbuf[s][rb+1][4*kq];
                        v4f h2v = *(const v4f*)&hbuf[s][rb+2][4*kq];
                        v4f h3v = *(const v4f*)&hbuf[s][rb+3][4*kq];
                        PK_FMA_LO(a0, h0.xy,  wsh[4*kq+0]); PK_FMA_HI(a0, h0.xy,  wsh[4*kq+1]);
                        PK_FMA_LO(a0, h0.zw,  wsh[4*kq+2]); PK_FMA_HI(a0, h0.zw,  wsh[4*kq+3]);
                        PK_FMA_LO(a1, h1v.xy, wsh[4*kq+0]); PK_FMA_HI(a1, h1v.xy, wsh[4*kq+1]);
                        PK_FMA_LO(a1, h1v.zw, wsh[4*kq+2]); PK_FMA_HI(a1, h1v.zw, wsh[4*kq+3]);
                        PK_FMA_LO(a2, h2v.xy, wsh[4*kq+0]); PK_FMA_HI(a2, h2v.xy, wsh[4*kq+1]);
                        PK_FMA_LO(a2, h2v.zw, wsh[4*kq+2]); PK_FMA_HI(a2, h2v.zw, wsh[4*kq+3]);
                        PK_FMA_LO(a3, h3v.xy, wsh[4*kq+0]); PK_FMA_HI(a3, h3v.xy, wsh[4*kq+1]);
                        PK_FMA_LO(a3, h3v.zw, wsh[4*kq+2]); PK_FMA_HI(a3, h3v.zw, wsh[4*kq+3]);
                    }
                    v2f o0 = { fmaxf(a0.x + breg.x, 0.f), fmaxf(a0.y + breg.y, 0.f) };
                    v2f o1 = { fmaxf(a1.x + breg.x, 0.f), fmaxf(a1.y + breg.y, 0.f) };
                    v2f o2 = { fmaxf(a2.x + breg.x, 0.f), fmaxf(a2.y + breg.y, 0.f) };
                    v2f o3 = { fmaxf(a3.x + breg.x, 0.f), fmaxf(a3.y + breg.y, 0.f) };
                    float* dst = x2g + ((size_t)b * T_SEQ + (size_t)c * 8 + rb) * 128 + 2 * u;
                    *(v2f*)dst         = o0;
                    *(v2f*)(dst + 128) = o1;
                    *(v2f*)(dst + 256) = o2;
                    *(v2f*)(dst + 384) = o3;
                    __threadfence();
                    if (lane == 0)
                        __hip_atomic_store(myflag, c + 1, __ATOMIC_RELEASE,
                                           __HIP_MEMORY_SCOPE_AGENT);
                }
            }
            __syncthreads();
        }
    } else {
        // ================== family 2: hopf2 -> h2 -> h3 -> out ==================
        for (int it = 0; it < NCH + 4; ++it) {
            if (wid == 0) {                  // poll+load chunk it; compute it-1
                const int c = it;
                v2f g0, g1, g2, g3, g4, g5, g6, g7;
                const bool ld = (c < NCH);
                if (ld) {
                    const int tgt = c + 1;
                    while (__hip_atomic_load(flags + b, __ATOMIC_ACQUIRE,
                                             __HIP_MEMORY_SCOPE_AGENT) < tgt ||
                           __hip_atomic_load(flags + 256 + b, __ATOMIC_ACQUIRE,
                                             __HIP_MEMORY_SCOPE_AGENT) < tgt)
                        __builtin_amdgcn_s_sleep(2);
                    const float* src = x2g + ((size_t)b * T_SEQ + (size_t)c * 8) * 128 + 2 * lane;
                    g0 = *(const v2f*)(src);
                    g1 = *(const v2f*)(src + 128);
                    g2 = *(const v2f*)(src + 256);
                    g3 = *(const v2f*)(src + 384);
                    g4 = *(const v2f*)(src + 512);
                    g5 = *(const v2f*)(src + 640);
                    g6 = *(const v2f*)(src + 768);
                    g7 = *(const v2f*)(src + 896);
                }
                const int cc2 = c - 1;
                if (0 <= cc2 && cc2 < NCH) {
                    const int s = cc2 & 1;
                    for (int j = 0; j < CCH; ++j) {
                        v2f f = *(const v2f*)&fbuf[s][j][2*lane];
                        const float dcr = SD * f.x, dci = SD * f.y;
                        float zr = zH.x, zi = zH.y;
#pragma unroll 2
                        for (int st = 0; st < NSTEP; ++st) {
                            float wr = fmaf(-domH, zi, dcr);
                            float wi = fmaf( domH, zr, dci);
                            float r2 = fmaf(zr, zr, zi * zi);
                            float g  = fmaf(-DT_C, r2, C1);
                            zr = fmaf(g, zr, wr);
                            zi = fmaf(g, zi, wi);
                        }
                        zH.x = zr; zH.y = zi;
                        *(v2f*)&zring[s][j][2*lane] = zH;
                    }
                }
                if (ld) {
                    const int sn = c & 1;
                    *(v2f*)&fbuf[sn][0][2*lane] = g0;
                    *(v2f*)&fbuf[sn][1][2*lane] = g1;
                    *(v2f*)&fbuf[sn][2][2*lane] = g2;
                    *(v2f*)&fbuf[sn][3][2*lane] = g3;
                    *(v2f*)&fbuf[sn][4][2*lane] = g4;
                    *(v2f*)&fbuf[sn][5][2*lane] = g5;
                    *(v2f*)&fbuf[sn][6][2*lane] = g6;
                    *(v2f*)&fbuf[sn][7][2*lane] = g7;
                }
            } else if (wid == 1) {           // h2 GEMM, chunk it-2
                const int c = it - 2;
                if (0 <= c && c < NCH) {
                    const int s = c & 1;
                    const int rg = lane >> 5, r0 = rg * 4;
                    v2f a0 = {0,0}, a1 = {0,0}, a2 = {0,0}, a3 = {0,0};
#pragma unroll
                    for (int kq = 0; kq < 16; ++kq) {
                        v4f zv0 = *(const v4f*)&zring[s][r0+0][4*kq];
                        v4f zv1 = *(const v4f*)&zring[s][r0+1][4*kq];
                        v4f zv2 = *(const v4f*)&zring[s][r0+2][4*kq];
                        v4f zv3 = *(const v4f*)&zring[s][r0+3][4*kq];
                        PK_FMA_LO(a0, zv0.xy, wsh[4*kq+0]); PK_FMA_HI(a0, zv0.xy, wsh[4*kq+1]);
                        PK_FMA_LO(a0, zv0.zw, wsh[4*kq+2]); PK_FMA_HI(a0, zv0.zw, wsh[4*kq+3]);
                        PK_FMA_LO(a1, zv1.xy, wsh[4*kq+0]); PK_FMA_HI(a1, zv1.xy, wsh[4*kq+1]);
                        PK_FMA_LO(a1, zv1.zw, wsh[4*kq+2]); PK_FMA_HI(a1, zv1.zw, wsh[4*kq+3]);
                        PK_FMA_LO(a2, zv2.xy, wsh[4*kq+0]); PK_FMA_HI(a2, zv2.xy, wsh[4*kq+1]);
                        PK_FMA_LO(a2, zv2.zw, wsh[4*kq+2]); PK_FMA_HI(a2, zv2.zw, wsh[4*kq+3]);
                        PK_FMA_LO(a3, zv3.xy, wsh[4*kq+0]); PK_FMA_HI(a3, zv3.xy, wsh[4*kq+1]);
                        PK_FMA_LO(a3, zv3.zw, wsh[4*kq+2]); PK_FMA_HI(a3, zv3.zw, wsh[4*kq+3]);
                    }
#pragma unroll 4
                    for (int kq = 16; kq < 32; ++kq) {
                        v4f zv0 = *(const v4f*)&zring[s][r0+0][4*kq];
                        v4f zv1 = *(const v4f*)&zring[s][r0+1][4*kq];
                        v4f zv2 = *(const v4f*)&zring[s][r0+2][4*kq];
                        v4f zv3 = *(const v4f*)&zring[s][r0+3][4*kq];
                        v2f w0 = WpL[(4*kq-64)*32 + cp];
                        v2f w1 = WpL[(4*kq-63)*32 + cp];
                        v2f w2 = WpL[(4*kq-62)*32 + cp];
                        v2f w3 = WpL[(4*kq-61)*32 + cp];
                        PK_FMA_LO(a0, zv0.xy, w0); PK_FMA_HI(a0, zv0.xy, w1);
                        PK_FMA_LO(a0, zv0.zw, w2); PK_FMA_HI(a0, zv0.zw, w3);
                        PK_FMA_LO(a1, zv1.xy, w0); PK_FMA_HI(a1, zv1.xy, w1);
                        PK_FMA_LO(a1, zv1.zw, w2); PK_FMA_HI(a1, zv1.zw, w3);
                        PK_FMA_LO(a2, zv2.xy, w0); PK_FMA_HI(a2, zv2.xy, w1);
                        PK_FMA_LO(a2, zv2.zw, w2); PK_FMA_HI(a2, zv2.zw, w3);
                        PK_FMA_LO(a3, zv3.xy, w0); PK_FMA_HI(a3, zv3.xy, w1);
                        PK_FMA_LO(a3, zv3.zw, w2); PK_FMA_HI(a3, zv3.zw, w3);
                    }
                    v2f o0 = { fmaxf(a0.x + breg.x, 0.f), fmaxf(a0.y + breg.y, 0.f) };
                    v2f o1 = { fmaxf(a1.x + breg.x, 0.f), fmaxf(a1.y + breg.y, 0.f) };
                    v2f o2 = { fmaxf(a2.x + breg.x, 0.f), fmaxf(a2.y + breg.y, 0.f) };
                    v2f o3 = { fmaxf(a3.x + breg.x, 0.f), fmaxf(a3.y + breg.y, 0.f) };
                    *(v2f*)&hbuf[s][r0+0][2*cp] = o0;
                    *(v2f*)&hbuf[s][r0+1][2*cp] = o1;
                    *(v2f*)&hbuf[s][r0+2][2*cp] = o2;
                    *(v2f*)&hbuf[s][r0+3][2*cp] = o3;
                }
            } else {                         // h3 tanh chunk it-3; out it-4
                const int c = it - 3;
                if (0 <= c && c < NCH && lane < 40) {
                    const int s = c & 1, rb = (wid - 2) * 4;
                    const int rr = lane / 20;
                    const int r0 = rb + rr, r1 = rb + rr + 2;
                    float a0 = 0.f, a1 = 0.f;
#pragma unroll
                    for (int kq = 0; kq < 16; ++kq) {
                        v4f hA = *(const v4f*)&hbuf[s][r0][4*kq];
                        v4f hB = *(const v4f*)&hbuf[s][r1][4*kq];
                        a0 = fmaf(hA.x, wsh[2*kq].x,   a0);
                        a0 = fmaf(hA.y, wsh[2*kq].y,   a0);
                        a0 = fmaf(hA.z, wsh[2*kq+1].x, a0);
                        a0 = fmaf(hA.w, wsh[2*kq+1].y, a0);
                        a1 = fmaf(hB.x, wsh[2*kq].x,   a1);
                        a1 = fmaf(hB.y, wsh[2*kq].y,   a1);
                        a1 = fmaf(hB.z, wsh[2*kq+1].x, a1);
                        a1 = fmaf(hB.w, wsh[2*kq+1].y, a1);
                    }
                    h3b[s][r0][jj] = fast_tanh(a0 + bscal);
                    h3b[s][r1][jj] = fast_tanh(a1 + bscal);
                }
                if (wid == 2) {              // logits, chunk it-4
                    const int co = it - 4;
                    if (0 <= co && co < NCH && lane < 16) {
                        const int s = co & 1;
                        const int r = lane >> 1, ccx = lane & 1;
                        float a = bhs[ccx];
#pragma unroll 4
                        for (int p = 0; p < 20; ++p)
                            a = fmaf(h3b[s][r][p], Whs[p * 2 + ccx], a);
                        out[(size_t)b * (T_SEQ * 2) + (co * 8 + r) * 2 + ccx] = a;
                    }
                }
            }
            __syncthreads();
        }
    }
}

// ---------------------------------------------------------------------------
extern "C" void kernel_launch(void* const* d_in, const int* in_sizes, int n_in,
                              void* d_out, int out_size, void* d_ws, size_t ws_size,
                              hipStream_t stream) {
    const int*   x   = (const int*)  d_in[0];
    const float* E   = (const float*)d_in[1];
    const float* W1r = (const float*)d_in[2];
    const float* b1r = (const float*)d_in[3];
    const float* W1i = (const float*)d_in[4];
    const float* b1i = (const float*)d_in[5];
    const float* om1 = (const float*)d_in[6];
    const float* Wp1 = (const float*)d_in[7];
    const float* bp1 = (const float*)d_in[8];
    const float* W2r = (const float*)d_in[9];
    const float* b2r = (const float*)d_in[10];
    const float* W2i = (const float*)d_in[11];
    const float* b2i = (const float*)d_in[12];
    const float* om2 = (const float*)d_in[13];
    const float* Wp2 = (const float*)d_in[14];
    const float* bp2 = (const float*)d_in[15];
    const float* Wpr = (const float*)d_in[16];
    const float* bpr = (const float*)d_in[17];
    const float* Wh  = (const float*)d_in[18];
    const float* bh  = (const float*)d_in[19];

    float* tab   = (float*)d_ws;                       // 32000x128 = 16.4 MB
    float* x2g   = tab + (size_t)NVOC * 128;           // 256x512x128 = 67.1 MB
    int*   flags = (int*)(x2g + (size_t)B_BAT * T_SEQ * 128);   // 512 ints

    hipMemsetAsync(flags, 0, 512 * sizeof(int), stream);
    k0_table<<<NVOC / 128, 256, 0, stream>>>(E, W1r, b1r, W1i, b1i, tab);
    donn_split<<<2 * B_BAT, 256, 0, stream>>>(tab, x, om1, om2,
                                              Wp1, bp1, W2r, b2r, W2i, b2i,
                                              Wp2, bp2, Wpr, bpr, Wh, bh,
                                              x2g, flags, (float*)d_out);
}

// Round 11
// 254.022 us; speedup vs baseline: 5.9632x; 5.9632x over previous
//
#include <hip/hip_runtime.h>

#define T_SEQ 512
#define B_BAT 256
#define ED_ 100
#define NVOC 32000
#define DT_C 1e-3f
#define SC_C 0.2f
#define MU_C 1.0f
#define NSTEP 20
#define CCH 8                 // tokens per pipeline chunk
#define NCH (T_SEQ / CCH)     // 64 chunks
#define NIT (NCH + 6)         // pipeline depth 7 stages

typedef float v2f __attribute__((ext_vector_type(2)));
typedef float v4f __attribute__((ext_vector_type(4)));
typedef float f32x4 __attribute__((ext_vector_type(4)));
typedef short bf16x8 __attribute__((ext_vector_type(8)));

// packed FMA, scalar splat from LO half of pair sv:  acc.{x,y} += sv.x * w.{x,y}
#define PK_FMA_LO(acc, sv, w)                                                  \
    asm("v_pk_fma_f32 %0, %1, %2, %0 op_sel:[0,0,0] op_sel_hi:[0,1,1]"         \
        : "+v"(acc) : "v"(sv), "v"(w))
// packed FMA, scalar splat from HI half of pair sv:  acc.{x,y} += sv.y * w.{x,y}
#define PK_FMA_HI(acc, sv, w)                                                  \
    asm("v_pk_fma_f32 %0, %1, %2, %0 op_sel:[1,0,0] op_sel_hi:[1,1,1]"         \
        : "+v"(acc) : "v"(sv), "v"(w))

// 3-term bf16x2-compensated MFMA accumulate: c += (ah+al)*(bh+bl) - al*bl
#define MFMA3(c_, ah_, al_, bh_, bl_)                                          \
    c_ = __builtin_amdgcn_mfma_f32_16x16x32_bf16(ah_, bh_, c_, 0, 0, 0);       \
    c_ = __builtin_amdgcn_mfma_f32_16x16x32_bf16(ah_, bl_, c_, 0, 0, 0);       \
    c_ = __builtin_amdgcn_mfma_f32_16x16x32_bf16(al_, bh_, c_, 0, 0, 0);

__device__ __forceinline__ unsigned pack2_bf16(float a, float b) {
    unsigned r;
    asm("v_cvt_pk_bf16_f32 %0, %1, %2" : "=v"(r) : "v"(a), "v"(b));
    return r;
}

__device__ __forceinline__ float fast_tanh(float x) {
    float e = __expf(2.f * x);
    return 1.f - 2.f * __builtin_amdgcn_rcpf(e + 1.f);
}

// ---------------------------------------------------------------------------
// K0: tab[v][c] = relu(E[v] @ W1cat + b1cat), c interleaved (2u+p). 250 blocks.
// ---------------------------------------------------------------------------
__global__ __launch_bounds__(256) void k0_table(
    const float* __restrict__ E,
    const float* __restrict__ W1r, const float* __restrict__ b1r,
    const float* __restrict__ W1i, const float* __restrict__ b1i,
    float* __restrict__ tab)
{
    __shared__ float embT[128 * 104];
    __shared__ float Wc[100 * 128];
    __shared__ float bias[128];
    const int tid = threadIdx.x;
    const int row0g = blockIdx.x * 128;

    for (int idx = tid; idx < 100 * 128; idx += 256) {
        int k = idx >> 7, c = idx & 127;
        Wc[idx] = (c & 1) ? W1i[k * 64 + (c >> 1)] : W1r[k * 64 + (c >> 1)];
    }
    if (tid < 128) bias[tid] = (tid & 1) ? b1i[tid >> 1] : b1r[tid >> 1];
    {
        int r = tid >> 1, half = tid & 1;
        const float4* src = (const float4*)(E + (size_t)(row0g + r) * ED_);
        float4* dst = (float4*)&embT[r * 104];
        for (int j = half; j < 25; j += 2) dst[j] = src[j];
    }
    __syncthreads();

    const int col0 = (tid & 15) * 8;
    const int row0 = (tid >> 4) * 8;
    float acc[8][8];
#pragma unroll
    for (int i = 0; i < 8; ++i)
#pragma unroll
        for (int j = 0; j < 8; ++j) acc[i][j] = 0.f;

    for (int k0 = 0; k0 < 100; k0 += 4) {
        float ev[8][4];
#pragma unroll
        for (int i = 0; i < 8; ++i)
            *(float4*)ev[i] = *(const float4*)&embT[(row0 + i) * 104 + k0];
#pragma unroll
        for (int kk = 0; kk < 4; ++kk) {
            float4 wA = *(const float4*)&Wc[(k0 + kk) * 128 + col0];
            float4 wB = *(const float4*)&Wc[(k0 + kk) * 128 + col0 + 4];
#pragma unroll
            for (int i = 0; i < 8; ++i) {
                float e = ev[i][kk];
                acc[i][0] = fmaf(e, wA.x, acc[i][0]);
                acc[i][1] = fmaf(e, wA.y, acc[i][1]);
                acc[i][2] = fmaf(e, wA.z, acc[i][2]);
                acc[i][3] = fmaf(e, wA.w, acc[i][3]);
                acc[i][4] = fmaf(e, wB.x, acc[i][4]);
                acc[i][5] = fmaf(e, wB.y, acc[i][5]);
                acc[i][6] = fmaf(e, wB.z, acc[i][6]);
                acc[i][7] = fmaf(e, wB.w, acc[i][7]);
            }
        }
    }
#pragma unroll
    for (int i = 0; i < 8; ++i) {
        float4 o0, o1;
        o0.x = fmaxf(acc[i][0] + bias[col0 + 0], 0.f);
        o0.y = fmaxf(acc[i][1] + bias[col0 + 1], 0.f);
        o0.z = fmaxf(acc[i][2] + bias[col0 + 2], 0.f);
        o0.w = fmaxf(acc[i][3] + bias[col0 + 3], 0.f);
        o1.x = fmaxf(acc[i][4] + bias[col0 + 4], 0.f);
        o1.y = fmaxf(acc[i][5] + bias[col0 + 5], 0.f);
        o1.z = fmaxf(acc[i][6] + bias[col0 + 6], 0.f);
        o1.w = fmaxf(acc[i][7] + bias[col0 + 7], 0.f);
        size_t base = (size_t)(row0g + row0 + i) * 128 + col0;
        *(float4*)&tab[base] = o0;
        *(float4*)&tab[base + 4] = o1;
    }
}

// ---------------------------------------------------------------------------
// Fused pipeline (round-9 structure). W2/W3 (h1/h2 GEMMs) now use bf16x2-
// compensated MFMA: z rings stored as bf16 hi/lo pairs (XOR-swizzled),
// weights as bf16 hi/lo column-major fragments in LDS.
// ---------------------------------------------------------------------------
__global__ __launch_bounds__(512, 1) void donn_pipe(
    const float* __restrict__ tab, const int* __restrict__ xin,
    const float* __restrict__ om1, const float* __restrict__ om2,
    const float* __restrict__ Wp1, const float* __restrict__ bp1,
    const float* __restrict__ W2r, const float* __restrict__ b2r,
    const float* __restrict__ W2i, const float* __restrict__ b2i,
    const float* __restrict__ Wp2, const float* __restrict__ bp2,
    const float* __restrict__ Wpr, const float* __restrict__ bpr,
    const float* __restrict__ Wh,  const float* __restrict__ bh,
    float* __restrict__ out)
{
    // B-fragments: WB[col][kpair] u32, swizzled (q ^ ((col&7)<<2)). 16KB each.
    __shared__ __align__(16) unsigned WB1h[4096], WB1l[4096];
    __shared__ __align__(16) unsigned WB2h[4096], WB2l[4096];
    __shared__ __align__(16) v2f   W2P[64 * 64];     // x2 weights (r,i) pairs
    __shared__ __align__(16) float WprT[20 * 68];
    // A-rings: [slot*512 + t*64 + (u ^ (t<<2))] u32 of (bf16 zr, bf16 zi).
    // Sized 1536 so reads at rows 8..15 (discarded C rows) stay in-array.
    __shared__ __align__(16) unsigned z1h_[1536], z1l_[1536];
    __shared__ __align__(16) unsigned z2h_[1536], z2l_[1536];
    __shared__ __align__(16) float x2r_[2][CCH][128];  // x2 ring (fp32 pairs)
    __shared__ __align__(16) float fbuf[2][CCH][128];  // hopf1 forcing ring
    __shared__ __align__(16) float h1b_[2][CCH][64];
    __shared__ __align__(16) float h2b_[2][CCH][64];
    __shared__ float h3b_[2][CCH][20];
    __shared__ float bp1s[64], bp2s[64], bprs[20], Whs[40], bhs[2];
    __shared__ v2f   b2P[64];

    const int tid = threadIdx.x, wid = tid >> 6, lane = tid & 63;
    const int b = blockIdx.x;
    const int* xb = xin + b * T_SEQ;

    // ---- stage weights into LDS ----
    for (int idx = tid; idx < 64 * 64; idx += 512) {
        int col = idx >> 6, q = idx & 63;           // kI pair q -> kR rows q, 64+q
        int sidx = col * 64 + (q ^ ((col & 7) << 2));
        float w0 = Wp1[q * 64 + col], w1 = Wp1[(64 + q) * 64 + col];
        unsigned h1v = pack2_bf16(w0, w1);
        float r0 = w0 - __uint_as_float(h1v << 16);
        float r1 = w1 - __uint_as_float(h1v & 0xFFFF0000u);
        WB1h[sidx] = h1v; WB1l[sidx] = pack2_bf16(r0, r1);
        float v0 = Wp2[q * 64 + col], v1 = Wp2[(64 + q) * 64 + col];
        unsigned h2v = pack2_bf16(v0, v1);
        float s0 = v0 - __uint_as_float(h2v << 16);
        float s1 = v1 - __uint_as_float(h2v & 0xFFFF0000u);
        WB2h[sidx] = h2v; WB2l[sidx] = pack2_bf16(s0, s1);
    }
    for (int idx = tid; idx < 64 * 64; idx += 512) {
        int k = idx >> 6, u = idx & 63;
        W2P[idx] = (v2f){ W2r[k * 64 + u], W2i[k * 64 + u] };
    }
    for (int idx = tid; idx < 20 * 68; idx += 512) {
        int j = idx / 68, k = idx % 68;
        WprT[idx] = (k < 64) ? Wpr[k * 20 + j] : 0.f;
    }
    if (tid < 64) { bp1s[tid] = bp1[tid]; bp2s[tid] = bp2[tid];
                    b2P[tid] = (v2f){ b2r[tid], b2i[tid] }; }
    if (tid < 40) Whs[tid] = Wh[tid];
    if (tid < 20) bprs[tid] = bpr[tid];
    if (tid < 2)  bhs[tid]  = bh[tid];

    const float C1 = 1.0f + DT_C * MU_C;
    const float SD = DT_C * SC_C;
    v2f zH = { 0.1f, 0.0f };
    float domH = 0.f;
    if (wid == 0) domH = DT_C * om1[lane];
    if (wid == 1) domH = DT_C * om2[lane];

    if (wid == 0) {    // prologue: stage chunk-0 forcing
        const float* tl = tab + 2 * lane;
        v2f g0 = *(const v2f*)(tl + (size_t)xb[0] * 128);
        v2f g1 = *(const v2f*)(tl + (size_t)xb[1] * 128);
        v2f g2 = *(const v2f*)(tl + (size_t)xb[2] * 128);
        v2f g3 = *(const v2f*)(tl + (size_t)xb[3] * 128);
        v2f g4 = *(const v2f*)(tl + (size_t)xb[4] * 128);
        v2f g5 = *(const v2f*)(tl + (size_t)xb[5] * 128);
        v2f g6 = *(const v2f*)(tl + (size_t)xb[6] * 128);
        v2f g7 = *(const v2f*)(tl + (size_t)xb[7] * 128);
        *(v2f*)&fbuf[0][0][2*lane] = g0; *(v2f*)&fbuf[0][1][2*lane] = g1;
        *(v2f*)&fbuf[0][2][2*lane] = g2; *(v2f*)&fbuf[0][3][2*lane] = g3;
        *(v2f*)&fbuf[0][4][2*lane] = g4; *(v2f*)&fbuf[0][5][2*lane] = g5;
        *(v2f*)&fbuf[0][6][2*lane] = g6; *(v2f*)&fbuf[0][7][2*lane] = g7;
    }
    __syncthreads();

    for (int it = 0; it < NIT; ++it) {
        if (wid == 0) {                      // hopf1, chunk it -> z1 bf16 ring
            const int c = it;
            if (c < NCH) {
                const int s = c & 1;
                const int cn = (c + 1 < NCH) ? (c + 1) : (NCH - 1);
                const int sn = cn & 1;
                const float* tl = tab + 2 * lane;
                const int* xc = xb + cn * 8;
                v2f g0 = *(const v2f*)(tl + (size_t)xc[0] * 128);
                v2f g1 = *(const v2f*)(tl + (size_t)xc[1] * 128);
                v2f g2 = *(const v2f*)(tl + (size_t)xc[2] * 128);
                v2f g3 = *(const v2f*)(tl + (size_t)xc[3] * 128);
                v2f g4 = *(const v2f*)(tl + (size_t)xc[4] * 128);
                v2f g5 = *(const v2f*)(tl + (size_t)xc[5] * 128);
                v2f g6 = *(const v2f*)(tl + (size_t)xc[6] * 128);
                v2f g7 = *(const v2f*)(tl + (size_t)xc[7] * 128);
                for (int j = 0; j < CCH; ++j) {
                    v2f f = *(const v2f*)&fbuf[s][j][2*lane];
                    const float dcr = SD * f.x, dci = SD * f.y;
                    float zr = zH.x, zi = zH.y;
#pragma unroll 2
                    for (int st = 0; st < NSTEP; ++st) {
                        float wr = fmaf(-domH, zi, dcr);
                        float wi = fmaf( domH, zr, dci);
                        float r2 = fmaf(zr, zr, zi * zi);
                        float g  = fmaf(-DT_C, r2, C1);
                        zr = fmaf(g, zr, wr);
                        zi = fmaf(g, zi, wi);
                    }
                    zH.x = zr; zH.y = zi;
                    unsigned zpk = pack2_bf16(zr, zi);
                    float rx = zr - __uint_as_float(zpk << 16);
                    float ry = zi - __uint_as_float(zpk & 0xFFFF0000u);
                    unsigned zlk = pack2_bf16(rx, ry);
                    const int widx = s * 512 + j * 64 + (lane ^ (j << 2));
                    z1h_[widx] = zpk; z1l_[widx] = zlk;
                }
                *(v2f*)&fbuf[sn][0][2*lane] = g0;
                *(v2f*)&fbuf[sn][1][2*lane] = g1;
                *(v2f*)&fbuf[sn][2][2*lane] = g2;
                *(v2f*)&fbuf[sn][3][2*lane] = g3;
                *(v2f*)&fbuf[sn][4][2*lane] = g4;
                *(v2f*)&fbuf[sn][5][2*lane] = g5;
                *(v2f*)&fbuf[sn][6][2*lane] = g6;
                *(v2f*)&fbuf[sn][7][2*lane] = g7;
            }
        } else if (wid == 1) {               // hopf2, chunk it-3 -> z2 bf16 ring
            const int c = it - 3;
            if (0 <= c && c < NCH) {
                const int s = c & 1;
                for (int j = 0; j < CCH; ++j) {
                    v2f f = *(const v2f*)&x2r_[s][j][2*lane];
                    const float dcr = SD * f.x, dci = SD * f.y;
                    float zr = zH.x, zi = zH.y;
#pragma unroll 2
                    for (int st = 0; st < NSTEP; ++st) {
                        float wr = fmaf(-domH, zi, dcr);
                        float wi = fmaf( domH, zr, dci);
                        float r2 = fmaf(zr, zr, zi * zi);
                        float g  = fmaf(-DT_C, r2, C1);
                        zr = fmaf(g, zr, wr);
                        zi = fmaf(g, zi, wi);
                    }
                    zH.x = zr; zH.y = zi;
                    unsigned zpk = pack2_bf16(zr, zi);
                    float rx = zr - __uint_as_float(zpk << 16);
                    float ry = zi - __uint_as_float(zpk & 0xFFFF0000u);
                    unsigned zlk = pack2_bf16(rx, ry);
                    const int widx = s * 512 + j * 64 + (lane ^ (j << 2));
                    z2h_[widx] = zpk; z2l_[widx] = zlk;
                }
            }
        } else if (wid == 2) {               // h1 MFMA, chunk it-1
            const int c = it - 1;
            if (0 <= c && c < NCH) {
                const int s = c & 1;
                const int cw = lane & 15, grp = lane >> 4;
                f32x4 cA = {0,0,0,0}, cB = {0,0,0,0}, cC = {0,0,0,0}, cD = {0,0,0,0};
#pragma unroll
                for (int ks = 0; ks < 4; ++ks) {
                    const int Bb = ks * 4 + grp;
                    const int aidx = s * 512 + cw * 64 + 4 * (Bb ^ cw);
                    bf16x8 ah = *(const bf16x8*)&z1h_[aidx];
                    bf16x8 al = *(const bf16x8*)&z1l_[aidx];
                    const int wq = 4 * (Bb ^ (cw & 7));
                    bf16x8 b0h = *(const bf16x8*)&WB1h[(     cw) * 64 + wq];
                    bf16x8 b0l = *(const bf16x8*)&WB1l[(     cw) * 64 + wq];
                    bf16x8 b1h = *(const bf16x8*)&WB1h[(16 + cw) * 64 + wq];
                    bf16x8 b1l = *(const bf16x8*)&WB1l[(16 + cw) * 64 + wq];
                    bf16x8 b2h = *(const bf16x8*)&WB1h[(32 + cw) * 64 + wq];
                    bf16x8 b2l = *(const bf16x8*)&WB1l[(32 + cw) * 64 + wq];
                    bf16x8 b3h = *(const bf16x8*)&WB1h[(48 + cw) * 64 + wq];
                    bf16x8 b3l = *(const bf16x8*)&WB1l[(48 + cw) * 64 + wq];
                    MFMA3(cA, ah, al, b0h, b0l);
                    MFMA3(cB, ah, al, b1h, b1l);
                    MFMA3(cC, ah, al, b2h, b2l);
                    MFMA3(cD, ah, al, b3h, b3l);
                }
                if (grp < 2) {
                    const int r0 = grp * 4;
                    const float bias0 = bp1s[cw],      bias1 = bp1s[16 + cw];
                    const float bias2 = bp1s[32 + cw], bias3 = bp1s[48 + cw];
#pragma unroll
                    for (int rg = 0; rg < 4; ++rg) {
                        h1b_[s][r0 + rg][     cw] = fmaxf(cA[rg] + bias0, 0.f);
                        h1b_[s][r0 + rg][16 + cw] = fmaxf(cB[rg] + bias1, 0.f);
                        h1b_[s][r0 + rg][32 + cw] = fmaxf(cC[rg] + bias2, 0.f);
                        h1b_[s][r0 + rg][48 + cw] = fmaxf(cD[rg] + bias3, 0.f);
                    }
                }
            }
        } else if (wid == 3) {               // h2 MFMA, chunk it-4
            const int c = it - 4;
            if (0 <= c && c < NCH) {
                const int s = c & 1;
                const int cw = lane & 15, grp = lane >> 4;
                f32x4 cA = {0,0,0,0}, cB = {0,0,0,0}, cC = {0,0,0,0}, cD = {0,0,0,0};
#pragma unroll
                for (int ks = 0; ks < 4; ++ks) {
                    const int Bb = ks * 4 + grp;
                    const int aidx = s * 512 + cw * 64 + 4 * (Bb ^ cw);
                    bf16x8 ah = *(const bf16x8*)&z2h_[aidx];
                    bf16x8 al = *(const bf16x8*)&z2l_[aidx];
                    const int wq = 4 * (Bb ^ (cw & 7));
                    bf16x8 b0h = *(const bf16x8*)&WB2h[(     cw) * 64 + wq];
                    bf16x8 b0l = *(const bf16x8*)&WB2l[(     cw) * 64 + wq];
                    bf16x8 b1h = *(const bf16x8*)&WB2h[(16 + cw) * 64 + wq];
                    bf16x8 b1l = *(const bf16x8*)&WB2l[(16 + cw) * 64 + wq];
                    bf16x8 b2h = *(const bf16x8*)&WB2h[(32 + cw) * 64 + wq];
                    bf16x8 b2l = *(const bf16x8*)&WB2l[(32 + cw) * 64 + wq];
                    bf16x8 b3h = *(const bf16x8*)&WB2h[(48 + cw) * 64 + wq];
                    bf16x8 b3l = *(const bf16x8*)&WB2l[(48 + cw) * 64 + wq];
                    MFMA3(cA, ah, al, b0h, b0l);
                    MFMA3(cB, ah, al, b1h, b1l);
                    MFMA3(cC, ah, al, b2h, b2l);
                    MFMA3(cD, ah, al, b3h, b3l);
                }
                if (grp < 2) {
                    const int r0 = grp * 4;
                    const float bias0 = bp2s[cw],      bias1 = bp2s[16 + cw];
                    const float bias2 = bp2s[32 + cw], bias3 = bp2s[48 + cw];
#pragma unroll
                    for (int rg = 0; rg < 4; ++rg) {
                        h2b_[s][r0 + rg][     cw] = fmaxf(cA[rg] + bias0, 0.f);
                        h2b_[s][r0 + rg][16 + cw] = fmaxf(cB[rg] + bias1, 0.f);
                        h2b_[s][r0 + rg][32 + cw] = fmaxf(cC[rg] + bias2, 0.f);
                        h2b_[s][r0 + rg][48 + cw] = fmaxf(cD[rg] + bias3, 0.f);
                    }
                }
            }
        } else if (wid == 4 || wid == 5) {   // x2 GEMM, chunk it-2 (pk pairs)
            const int c = it - 2;
            if (0 <= c && c < NCH) {
                const int s = c & 1;
                const int rb = (wid - 4) * 4;
                const int u = lane;
                v2f a0 = {0,0}, a1 = {0,0}, a2 = {0,0}, a3 = {0,0};
#pragma unroll 4
                for (int kq = 0; kq < 16; ++kq) {
                    v4f h0 = *(const v4f*)&h1b_[s][rb+0][4*kq];
                    v4f h1v = *(const v4f*)&h1b_[s][rb+1][4*kq];
                    v4f h2v = *(const v4f*)&h1b_[s][rb+2][4*kq];
                    v4f h3v = *(const v4f*)&h1b_[s][rb+3][4*kq];
                    v2f w0 = W2P[(4*kq+0)*64 + u];
                    v2f w1 = W2P[(4*kq+1)*64 + u];
                    v2f w2 = W2P[(4*kq+2)*64 + u];
                    v2f w3 = W2P[(4*kq+3)*64 + u];
                    PK_FMA_LO(a0, h0.xy, w0);  PK_FMA_HI(a0, h0.xy, w1);
                    PK_FMA_LO(a0, h0.zw, w2);  PK_FMA_HI(a0, h0.zw, w3);
                    PK_FMA_LO(a1, h1v.xy, w0); PK_FMA_HI(a1, h1v.xy, w1);
                    PK_FMA_LO(a1, h1v.zw, w2); PK_FMA_HI(a1, h1v.zw, w3);
                    PK_FMA_LO(a2, h2v.xy, w0); PK_FMA_HI(a2, h2v.xy, w1);
                    PK_FMA_LO(a2, h2v.zw, w2); PK_FMA_HI(a2, h2v.zw, w3);
                    PK_FMA_LO(a3, h3v.xy, w0); PK_FMA_HI(a3, h3v.xy, w1);
                    PK_FMA_LO(a3, h3v.zw, w2); PK_FMA_HI(a3, h3v.zw, w3);
                }
                v2f bb = b2P[u];
                v2f o0 = { fmaxf(a0.x + bb.x, 0.f), fmaxf(a0.y + bb.y, 0.f) };
                v2f o1 = { fmaxf(a1.x + bb.x, 0.f), fmaxf(a1.y + bb.y, 0.f) };
                v2f o2 = { fmaxf(a2.x + bb.x, 0.f), fmaxf(a2.y + bb.y, 0.f) };
                v2f o3 = { fmaxf(a3.x + bb.x, 0.f), fmaxf(a3.y + bb.y, 0.f) };
                *(v2f*)&x2r_[s][rb+0][2*u] = o0;
                *(v2f*)&x2r_[s][rb+1][2*u] = o1;
                *(v2f*)&x2r_[s][rb+2][2*u] = o2;
                *(v2f*)&x2r_[s][rb+3][2*u] = o3;
            }
        } else {                             // W6/W7: h3 tanh, chunk it-5
            const int c = it - 5;
            if (0 <= c && c < NCH && lane < 40) {
                const int s = c & 1;
                const int rb = (wid - 6) * 4;
                const int rr = lane / 20, j = lane % 20;
                const int r0 = rb + rr, r1 = rb + rr + 2;
                float a0 = 0.f, a1 = 0.f;
#pragma unroll 4
                for (int kq = 0; kq < 16; ++kq) {
                    float4 w  = *(const float4*)&WprT[j * 68 + 4*kq];
                    float4 hA = *(const float4*)&h2b_[s][r0][4*kq];
                    float4 hB = *(const float4*)&h2b_[s][r1][4*kq];
                    a0 = fmaf(hA.x, w.x, a0); a0 = fmaf(hA.y, w.y, a0);
                    a0 = fmaf(hA.z, w.z, a0); a0 = fmaf(hA.w, w.w, a0);
                    a1 = fmaf(hB.x, w.x, a1); a1 = fmaf(hB.y, w.y, a1);
                    a1 = fmaf(hB.z, w.z, a1); a1 = fmaf(hB.w, w.w, a1);
                }
                h3b_[s][r0][j] = fast_tanh(a0 + bprs[j]);
                h3b_[s][r1][j] = fast_tanh(a1 + bprs[j]);
            }
            if (wid == 6) {                  // logits, chunk it-6
                const int co = it - 6;
                if (0 <= co && co < NCH && lane < 16) {
                    const int s = co & 1;
                    const int r = lane >> 1, cc = lane & 1;
                    float a = bhs[cc];
#pragma unroll 4
                    for (int p = 0; p < 20; ++p)
                        a = fmaf(h3b_[s][r][p], Whs[p * 2 + cc], a);
                    const int t = co * CCH + r;
                    out[(size_t)b * (T_SEQ * 2) + t * 2 + cc] = a;
                }
            }
        }
        __syncthreads();
    }
}

// ---------------------------------------------------------------------------
extern "C" void kernel_launch(void* const* d_in, const int* in_sizes, int n_in,
                              void* d_out, int out_size, void* d_ws, size_t ws_size,
                              hipStream_t stream) {
    const int*   x   = (const int*)  d_in[0];
    const float* E   = (const float*)d_in[1];
    const float* W1r = (const float*)d_in[2];
    const float* b1r = (const float*)d_in[3];
    const float* W1i = (const float*)d_in[4];
    const float* b1i = (const float*)d_in[5];
    const float* om1 = (const float*)d_in[6];
    const float* Wp1 = (const float*)d_in[7];
    const float* bp1 = (const float*)d_in[8];
    const float* W2r = (const float*)d_in[9];
    const float* b2r = (const float*)d_in[10];
    const float* W2i = (const float*)d_in[11];
    const float* b2i = (const float*)d_in[12];
    const float* om2 = (const float*)d_in[13];
    const float* Wp2 = (const float*)d_in[14];
    const float* bp2 = (const float*)d_in[15];
    const float* Wpr = (const float*)d_in[16];
    const float* bpr = (const float*)d_in[17];
    const float* Wh  = (const float*)d_in[18];
    const float* bh  = (const float*)d_in[19];

    float* tab = (float*)d_ws;   // relu(E@W1cat+b1cat), [32000][128] — 16.4 MB

    k0_table<<<NVOC / 128, 256, 0, stream>>>(E, W1r, b1r, W1i, b1i, tab);
    donn_pipe<<<B_BAT, 512, 0, stream>>>(tab, x, om1, om2,
                                         Wp1, bp1, W2r, b2r, W2i, b2i,
                                         Wp2, bp2, Wpr, bpr, Wh, bh,
                                         (float*)d_out);
}